// Round 1
// baseline (798.579 us; speedup 1.0000x reference)
//
#include <hip/hip_runtime.h>

#define N_VERT 100000
#define N_EDGE 1600000

typedef __attribute__((ext_vector_type(8))) short short8;
typedef __attribute__((ext_vector_type(4))) float f32x4;

__device__ __forceinline__ unsigned short f2bf(float f) {
    unsigned int u = __float_as_uint(f);
    unsigned int r = (u + 0x7FFFu + ((u >> 16) & 1u)) >> 16;
    return (unsigned short)r;
}

// ---- CSR build ----------------------------------------------------------

__global__ void k_init(unsigned int* cnt) {
    int i = blockIdx.x * 256 + threadIdx.x;
    if (i < N_VERT) cnt[i] = 0u;
}

__global__ void k_count(const int* src, unsigned int* cnt) {
    int e = blockIdx.x * 256 + threadIdx.x;
    if (e < N_EDGE) atomicAdd(&cnt[src[e]], 1u);
}

__global__ void k_scan1(const unsigned int* cnt, unsigned int* off, unsigned int* part) {
    __shared__ unsigned int s[1024];
    int t = threadIdx.x;
    int i = blockIdx.x * 1024 + t;
    unsigned int v = (i < N_VERT) ? cnt[i] : 0u;
    s[t] = v;
    __syncthreads();
    for (int d = 1; d < 1024; d <<= 1) {
        unsigned int x = (t >= d) ? s[t - d] : 0u;
        __syncthreads();
        s[t] += x;
        __syncthreads();
    }
    if (i < N_VERT) off[i] = s[t] - v;          // local exclusive
    if (t == 1023) part[blockIdx.x] = s[t];     // chunk total
}

__global__ void k_scan2(unsigned int* part) {
    __shared__ unsigned int s[128];
    int t = threadIdx.x;
    unsigned int v = (t < 98) ? part[t] : 0u;
    s[t] = v;
    __syncthreads();
    for (int d = 1; d < 128; d <<= 1) {
        unsigned int x = (t >= d) ? s[t - d] : 0u;
        __syncthreads();
        s[t] += x;
        __syncthreads();
    }
    part[t] = s[t] - v;                          // exclusive over chunks
}

__global__ void k_addback(unsigned int* off, unsigned int* cur, const unsigned int* part) {
    int i = blockIdx.x * 256 + threadIdx.x;
    if (i < N_VERT) {
        unsigned int o = off[i] + part[i >> 10];
        off[i] = o;
        cur[i] = o;
    }
}

__global__ void k_place(const int* src, unsigned int* cur, unsigned int* eidx) {
    int e = blockIdx.x * 256 + threadIdx.x;
    if (e < N_EDGE) {
        unsigned int p = atomicAdd(&cur[src[e]], 1u);
        eidx[p] = (unsigned int)e;
    }
}

// ---- weight transpose + bf16 --------------------------------------------
// Wt[n][k] = W[k][n], bf16.  W1:256x256  W2:256x256  W3:256x64
__global__ void k_wt(const float* W1, const float* W2, const float* W3,
                     unsigned short* W1t, unsigned short* W2t, unsigned short* W3t) {
    int t = blockIdx.x * 256 + threadIdx.x;   // 147456 total
    if (t < 65536) {
        int n = t >> 8, k = t & 255;
        W1t[t] = f2bf(W1[k * 256 + n]);
    } else if (t < 131072) {
        int u = t - 65536;
        int n = u >> 8, k = u & 255;
        W2t[u] = f2bf(W2[k * 256 + n]);
    } else if (t < 147456) {
        int u = t - 131072;
        int n = u >> 8, k = u & 255;    // n < 64
        W3t[u] = f2bf(W3[k * 64 + n]);
    }
}

// ---- fused aggregate + MLP ----------------------------------------------

__device__ __forceinline__ void store8(unsigned char* base, int row, int feat0, const float* f) {
    union { short8 v; unsigned short u[8]; } p;
    for (int j = 0; j < 8; j++) p.u[j] = f2bf(f[j]);
    *(short8*)(base + row * 512 + ((feat0 * 2) ^ ((row & 7) << 4))) = p.v;
}

__device__ __forceinline__ void gemm_lds(const unsigned char* src, unsigned char* dst,
                                         const unsigned short* Wt, const float* bias,
                                         int NT, int tid) {
    int wave = tid >> 6, lane = tid & 63;
    int arow = wave * 16 + (lane & 15);
    int kb = (lane >> 4) * 8;
    int nl = lane & 15;
    int drow_base = wave * 16 + (lane >> 4) * 4;
    for (int nt = 0; nt < NT; ++nt) {
        float bv = bias[nt * 16 + nl];
        f32x4 acc = {bv, bv, bv, bv};
        const unsigned short* wp = Wt + (nt * 16 + nl) * 256 + kb;
        for (int k0 = 0; k0 < 8; k0++) {
            short8 a = *(const short8*)(src + arow * 512 + (((k0 * 32 + kb) * 2) ^ ((arow & 7) << 4)));
            short8 b = *(const short8*)(wp + k0 * 32);
            acc = __builtin_amdgcn_mfma_f32_16x16x32_bf16(a, b, acc, 0, 0, 0);
        }
        for (int i = 0; i < 4; i++) {
            float rv = acc[i];
            rv = rv > 0.f ? rv : 0.f;   // relu
            int row = drow_base + i;
            int col = nt * 16 + nl;
            *(unsigned short*)(dst + row * 512 + ((col * 2) ^ ((row & 7) << 4))) = f2bf(rv);
        }
    }
}

__global__ __launch_bounds__(256, 2) void k_mlp(
    const float* __restrict__ v_attr, const float* __restrict__ e_attr,
    const float* __restrict__ g, const int* __restrict__ batch,
    const unsigned int* __restrict__ cnt, const unsigned int* __restrict__ off,
    const unsigned int* __restrict__ eidx,
    const unsigned short* __restrict__ W1t, const unsigned short* __restrict__ W2t,
    const unsigned short* __restrict__ W3t,
    const float* __restrict__ b1, const float* __restrict__ b2, const float* __restrict__ b3,
    float* __restrict__ out)
{
    __shared__ __align__(16) unsigned char smem[65536];
    unsigned char* xs = smem;            // 64 rows x 256 bf16, swizzled
    unsigned char* hs = smem + 32768;
    const int tid = threadIdx.x;
    const int v0 = blockIdx.x * 64;

    // phase 0: assemble x = [v_attr | min | mean | sum | max | g[batch]]
    {
        int vl = tid >> 2, q = tid & 3;
        int v = v0 + vl;
        bool valid = v < N_VERT;
        float f[8];

        for (int c = 0; c < 2; c++) {
            int gi = q + c * 4;
            if (valid) {
                const float4* p = (const float4*)(v_attr + v * 64 + gi * 8);
                float4 a = p[0], b = p[1];
                f[0]=a.x; f[1]=a.y; f[2]=a.z; f[3]=a.w; f[4]=b.x; f[5]=b.y; f[6]=b.z; f[7]=b.w;
            } else {
                for (int j = 0; j < 8; j++) f[j] = 0.f;
            }
            store8(xs, vl, gi * 8, f);
        }

        float mn[8], mx[8], sm[8], me[8];
        for (int j = 0; j < 8; j++) { mn[j] = INFINITY; mx[j] = -INFINITY; sm[j] = 0.f; }
        unsigned int c_ = 0;
        if (valid) {
            c_ = cnt[v];
            unsigned int st = off[v];
            for (unsigned int j = 0; j < c_; j++) {
                unsigned int eid = eidx[st + j];
                const float4* p = (const float4*)(e_attr + eid * 32 + q * 8);
                float4 a = p[0], b = p[1];
                float t0[8] = {a.x, a.y, a.z, a.w, b.x, b.y, b.z, b.w};
                for (int jj = 0; jj < 8; jj++) {
                    float x = t0[jj];
                    mn[jj] = fminf(mn[jj], x);
                    mx[jj] = fmaxf(mx[jj], x);
                    sm[jj] += x;
                }
            }
        }
        if (c_ == 0) { for (int j = 0; j < 8; j++) { mn[j] = 0.f; mx[j] = 0.f; } }
        float inv = 1.0f / (float)(c_ > 1u ? c_ : 1u);
        for (int j = 0; j < 8; j++) me[j] = sm[j] * inv;
        store8(xs, vl,  64 + q * 8, mn);
        store8(xs, vl,  96 + q * 8, me);
        store8(xs, vl, 128 + q * 8, sm);
        store8(xs, vl, 160 + q * 8, mx);

        int b_ = valid ? batch[v] : 0;
        for (int c = 0; c < 2; c++) {
            int gi = q + c * 4;
            if (valid) {
                const float4* p = (const float4*)(g + b_ * 64 + gi * 8);
                float4 a = p[0], b = p[1];
                f[0]=a.x; f[1]=a.y; f[2]=a.z; f[3]=a.w; f[4]=b.x; f[5]=b.y; f[6]=b.z; f[7]=b.w;
            } else {
                for (int j = 0; j < 8; j++) f[j] = 0.f;
            }
            store8(xs, vl, 192 + gi * 8, f);
        }
    }
    __syncthreads();

    gemm_lds(xs, hs, W1t, b1, 16, tid);   // layer 1: 256 -> 256, relu
    __syncthreads();
    gemm_lds(hs, xs, W2t, b2, 16, tid);   // layer 2: 256 -> 256, relu
    __syncthreads();

    // layer 3: 256 -> 64, no relu, to global
    {
        int wave = tid >> 6, lane = tid & 63;
        int arow = wave * 16 + (lane & 15);
        int kb = (lane >> 4) * 8;
        int nl = lane & 15;
        for (int nt = 0; nt < 4; nt++) {
            float bv = b3[nt * 16 + nl];
            f32x4 acc = {bv, bv, bv, bv};
            const unsigned short* wp = W3t + (nt * 16 + nl) * 256 + kb;
            for (int k0 = 0; k0 < 8; k0++) {
                short8 a = *(const short8*)(xs + arow * 512 + (((k0 * 32 + kb) * 2) ^ ((arow & 7) << 4)));
                short8 b = *(const short8*)(wp + k0 * 32);
                acc = __builtin_amdgcn_mfma_f32_16x16x32_bf16(a, b, acc, 0, 0, 0);
            }
            for (int i = 0; i < 4; i++) {
                int row = wave * 16 + (lane >> 4) * 4 + i;
                int v = v0 + row;
                if (v < N_VERT) out[v * 64 + nt * 16 + nl] = acc[i];
            }
        }
    }
}

// ---- launch --------------------------------------------------------------

extern "C" void kernel_launch(void* const* d_in, const int* in_sizes, int n_in,
                              void* d_out, int out_size, void* d_ws, size_t ws_size,
                              hipStream_t stream) {
    const float* v_attr = (const float*)d_in[0];
    const int*   edge   = (const int*)d_in[1];      // [2, N_EDGE]; row 0 = src
    const float* e_attr = (const float*)d_in[2];
    const float* g      = (const float*)d_in[3];
    const int*   batch  = (const int*)d_in[4];
    const float* W1 = (const float*)d_in[5];
    const float* b1 = (const float*)d_in[6];
    const float* W2 = (const float*)d_in[7];
    const float* b2 = (const float*)d_in[8];
    const float* W3 = (const float*)d_in[9];
    const float* b3 = (const float*)d_in[10];
    float* out = (float*)d_out;

    unsigned char* ws = (unsigned char*)d_ws;
    unsigned int*   cnt  = (unsigned int*)(ws + 0);          // 400000 B
    unsigned int*   off  = (unsigned int*)(ws + 400000);     // 400000 B
    unsigned int*   cur  = (unsigned int*)(ws + 800000);     // 400000 B
    unsigned int*   eidx = (unsigned int*)(ws + 1200000);    // 6400000 B
    unsigned int*   part = (unsigned int*)(ws + 7600000);    // 512 B
    unsigned short* W1t  = (unsigned short*)(ws + 7600640);  // 131072 B
    unsigned short* W2t  = (unsigned short*)(ws + 7731712);  // 131072 B
    unsigned short* W3t  = (unsigned short*)(ws + 7862784);  // 32768 B

    const int* src = edge;  // first N_EDGE ints

    k_init   <<<391,  256,  0, stream>>>(cnt);
    k_count  <<<6250, 256,  0, stream>>>(src, cnt);
    k_scan1  <<<98,   1024, 0, stream>>>(cnt, off, part);
    k_scan2  <<<1,    128,  0, stream>>>(part);
    k_addback<<<391,  256,  0, stream>>>(off, cur, part);
    k_place  <<<6250, 256,  0, stream>>>(src, cur, eidx);
    k_wt     <<<576,  256,  0, stream>>>(W1, W2, W3, W1t, W2t, W3t);
    k_mlp    <<<1563, 256,  0, stream>>>(v_attr, e_attr, g, batch, cnt, off, eidx,
                                         W1t, W2t, W3t, b1, b2, b3, out);
}

// Round 3
// 712.784 us; speedup vs baseline: 1.1204x; 1.1204x over previous
//
#include <hip/hip_runtime.h>

#define N_VERT 100000
#define N_EDGE 1600000

typedef __attribute__((ext_vector_type(8))) short short8;
typedef __attribute__((ext_vector_type(4))) float f32x4;

__device__ __forceinline__ unsigned short f2bf(float f) {
    unsigned int u = __float_as_uint(f);
    unsigned int r = (u + 0x7FFFu + ((u >> 16) & 1u)) >> 16;
    return (unsigned short)r;
}
__device__ __forceinline__ float bf2f(unsigned short u) {
    return __uint_as_float(((unsigned int)u) << 16);
}

// ---- CSR build ----------------------------------------------------------

__global__ void k_init(unsigned int* cnt) {
    int i = blockIdx.x * 256 + threadIdx.x;
    if (i < N_VERT) cnt[i] = 0u;
}

__global__ void k_count(const int* src, unsigned int* cnt) {
    int e = blockIdx.x * 256 + threadIdx.x;
    if (e < N_EDGE) atomicAdd(&cnt[src[e]], 1u);
}

__global__ void k_scan1(const unsigned int* cnt, unsigned int* off, unsigned int* part) {
    __shared__ unsigned int s[1024];
    int t = threadIdx.x;
    int i = blockIdx.x * 1024 + t;
    unsigned int v = (i < N_VERT) ? cnt[i] : 0u;
    s[t] = v;
    __syncthreads();
    for (int d = 1; d < 1024; d <<= 1) {
        unsigned int x = (t >= d) ? s[t - d] : 0u;
        __syncthreads();
        s[t] += x;
        __syncthreads();
    }
    if (i < N_VERT) off[i] = s[t] - v;          // local exclusive
    if (t == 1023) part[blockIdx.x] = s[t];     // chunk total
}

__global__ void k_scan2(unsigned int* part) {
    __shared__ unsigned int s[128];
    int t = threadIdx.x;
    unsigned int v = (t < 98) ? part[t] : 0u;
    s[t] = v;
    __syncthreads();
    for (int d = 1; d < 128; d <<= 1) {
        unsigned int x = (t >= d) ? s[t - d] : 0u;
        __syncthreads();
        s[t] += x;
        __syncthreads();
    }
    part[t] = s[t] - v;                          // exclusive over chunks
}

__global__ void k_addback(unsigned int* off, unsigned int* cur, const unsigned int* part) {
    int i = blockIdx.x * 256 + threadIdx.x;
    if (i < N_VERT) {
        unsigned int o = off[i] + part[i >> 10];
        off[i] = o;
        cur[i] = o;
    }
}

// reorder+convert: e_sorted[p] = bf16(e_attr[e]) with p = CSR slot of edge e
__global__ void k_reorder(const int* __restrict__ src, const float* __restrict__ e_attr,
                          unsigned int* __restrict__ cur, unsigned short* __restrict__ es) {
    int e = blockIdx.x * 256 + threadIdx.x;
    if (e >= N_EDGE) return;
    unsigned int p = atomicAdd(&cur[src[e]], 1u);
    const float4* in = (const float4*)(e_attr + (size_t)e * 32);
    unsigned short* op = es + (size_t)p * 32;
    for (int h = 0; h < 4; h++) {
        float4 a = in[h * 2], b = in[h * 2 + 1];
        union { short8 v; unsigned short u[8]; } pk;
        pk.u[0] = f2bf(a.x); pk.u[1] = f2bf(a.y); pk.u[2] = f2bf(a.z); pk.u[3] = f2bf(a.w);
        pk.u[4] = f2bf(b.x); pk.u[5] = f2bf(b.y); pk.u[6] = f2bf(b.z); pk.u[7] = f2bf(b.w);
        *(short8*)(op + h * 8) = pk.v;
    }
}

// fallback placement (eidx permutation) when ws can't hold e_sorted
__global__ void k_place(const int* src, unsigned int* cur, unsigned int* eidx) {
    int e = blockIdx.x * 256 + threadIdx.x;
    if (e < N_EDGE) {
        unsigned int p = atomicAdd(&cur[src[e]], 1u);
        eidx[p] = (unsigned int)e;
    }
}

// ---- weight transpose + bf16 --------------------------------------------
__global__ void k_wt(const float* W1, const float* W2, const float* W3,
                     unsigned short* W1t, unsigned short* W2t, unsigned short* W3t) {
    int t = blockIdx.x * 256 + threadIdx.x;   // 147456 total
    if (t < 65536) {
        int n = t >> 8, k = t & 255;
        W1t[t] = f2bf(W1[k * 256 + n]);
    } else if (t < 131072) {
        int u = t - 65536;
        int n = u >> 8, k = u & 255;
        W2t[u] = f2bf(W2[k * 256 + n]);
    } else if (t < 147456) {
        int u = t - 131072;
        int n = u >> 8, k = u & 255;    // n < 64
        W3t[u] = f2bf(W3[k * 64 + n]);
    }
}

// ---- fused aggregate + MLP ----------------------------------------------

__device__ __forceinline__ void store8(unsigned char* base, int row, int feat0, const float* f) {
    union { short8 v; unsigned short u[8]; } p;
    for (int j = 0; j < 8; j++) p.u[j] = f2bf(f[j]);
    *(short8*)(base + row * 512 + ((feat0 * 2) ^ ((row & 7) << 4))) = p.v;
}

__device__ __forceinline__ void gemm_lds(const unsigned char* src, unsigned char* dst,
                                         const unsigned short* Wt, const float* bias,
                                         int NT, int tid) {
    int wave = tid >> 6, lane = tid & 63;
    int arow = wave * 16 + (lane & 15);
    int kb = (lane >> 4) * 8;
    int nl = lane & 15;
    int drow_base = wave * 16 + (lane >> 4) * 4;
    for (int nt = 0; nt < NT; ++nt) {
        float bv = bias[nt * 16 + nl];
        f32x4 acc = {bv, bv, bv, bv};
        const unsigned short* wp = Wt + (nt * 16 + nl) * 256 + kb;
        for (int k0 = 0; k0 < 8; k0++) {
            short8 a = *(const short8*)(src + arow * 512 + (((k0 * 32 + kb) * 2) ^ ((arow & 7) << 4)));
            short8 b = *(const short8*)(wp + k0 * 32);
            acc = __builtin_amdgcn_mfma_f32_16x16x32_bf16(a, b, acc, 0, 0, 0);
        }
        for (int i = 0; i < 4; i++) {
            float rv = acc[i];
            rv = rv > 0.f ? rv : 0.f;   // relu
            int row = drow_base + i;
            int col = nt * 16 + nl;
            *(unsigned short*)(dst + row * 512 + ((col * 2) ^ ((row & 7) << 4))) = f2bf(rv);
        }
    }
}

template <bool SORTED>
__global__ __launch_bounds__(256, 2) void k_mlp(
    const float* __restrict__ v_attr, const float* __restrict__ e_attr,
    const unsigned short* __restrict__ es,
    const float* __restrict__ g, const int* __restrict__ batch,
    const unsigned int* __restrict__ cnt, const unsigned int* __restrict__ off,
    const unsigned int* __restrict__ eidx,
    const unsigned short* __restrict__ W1t, const unsigned short* __restrict__ W2t,
    const unsigned short* __restrict__ W3t,
    const float* __restrict__ b1, const float* __restrict__ b2, const float* __restrict__ b3,
    float* __restrict__ out)
{
    __shared__ __align__(16) unsigned char smem[65536];
    unsigned char* xs = smem;            // 64 rows x 256 bf16, swizzled
    unsigned char* hs = smem + 32768;
    const int tid = threadIdx.x;
    const int v0 = blockIdx.x * 64;

    // phase 0: assemble x = [v_attr | min | mean | sum | max | g[batch]]
    {
        int vl = tid >> 2, q = tid & 3;
        int v = v0 + vl;
        bool valid = v < N_VERT;
        float f[8];

        for (int c = 0; c < 2; c++) {
            int gi = q + c * 4;
            if (valid) {
                const float4* p = (const float4*)(v_attr + (size_t)v * 64 + gi * 8);
                float4 a = p[0], b = p[1];
                f[0]=a.x; f[1]=a.y; f[2]=a.z; f[3]=a.w; f[4]=b.x; f[5]=b.y; f[6]=b.z; f[7]=b.w;
            } else {
                for (int j = 0; j < 8; j++) f[j] = 0.f;
            }
            store8(xs, vl, gi * 8, f);
        }

        float mn[8], mx[8], sm[8], me[8];
        for (int j = 0; j < 8; j++) { mn[j] = INFINITY; mx[j] = -INFINITY; sm[j] = 0.f; }
        unsigned int c_ = 0;
        if (valid) {
            c_ = cnt[v];
            unsigned int st = off[v];
            if (SORTED) {
                // contiguous, coalesced, independent 16B loads
                const unsigned short* ep = es + (size_t)st * 32 + q * 8;
                for (unsigned int j = 0; j < c_; j++) {
                    union { short8 v8; unsigned short u[8]; } r;
                    r.v8 = *(const short8*)(ep + (size_t)j * 32);
                    for (int jj = 0; jj < 8; jj++) {
                        float x = bf2f(r.u[jj]);
                        mn[jj] = fminf(mn[jj], x);
                        mx[jj] = fmaxf(mx[jj], x);
                        sm[jj] += x;
                    }
                }
            } else {
                for (unsigned int j = 0; j < c_; j++) {
                    unsigned int eid = eidx[st + j];
                    const float4* p = (const float4*)(e_attr + (size_t)eid * 32 + q * 8);
                    float4 a = p[0], b = p[1];
                    float t0[8] = {a.x, a.y, a.z, a.w, b.x, b.y, b.z, b.w};
                    for (int jj = 0; jj < 8; jj++) {
                        float x = t0[jj];
                        mn[jj] = fminf(mn[jj], x);
                        mx[jj] = fmaxf(mx[jj], x);
                        sm[jj] += x;
                    }
                }
            }
        }
        if (c_ == 0) { for (int j = 0; j < 8; j++) { mn[j] = 0.f; mx[j] = 0.f; } }
        float inv = 1.0f / (float)(c_ > 1u ? c_ : 1u);
        for (int j = 0; j < 8; j++) me[j] = sm[j] * inv;
        store8(xs, vl,  64 + q * 8, mn);
        store8(xs, vl,  96 + q * 8, me);
        store8(xs, vl, 128 + q * 8, sm);
        store8(xs, vl, 160 + q * 8, mx);

        int b_ = valid ? batch[v] : 0;
        for (int c = 0; c < 2; c++) {
            int gi = q + c * 4;
            if (valid) {
                const float4* p = (const float4*)(g + (size_t)b_ * 64 + gi * 8);
                float4 a = p[0], b = p[1];
                f[0]=a.x; f[1]=a.y; f[2]=a.z; f[3]=a.w; f[4]=b.x; f[5]=b.y; f[6]=b.z; f[7]=b.w;
            } else {
                for (int j = 0; j < 8; j++) f[j] = 0.f;
            }
            store8(xs, vl, 192 + gi * 8, f);
        }
    }
    __syncthreads();

    gemm_lds(xs, hs, W1t, b1, 16, tid);   // layer 1: 256 -> 256, relu
    __syncthreads();
    gemm_lds(hs, xs, W2t, b2, 16, tid);   // layer 2: 256 -> 256, relu
    __syncthreads();

    // layer 3: 256 -> 64, no relu, to global
    {
        int wave = tid >> 6, lane = tid & 63;
        int arow = wave * 16 + (lane & 15);
        int kb = (lane >> 4) * 8;
        int nl = lane & 15;
        for (int nt = 0; nt < 4; nt++) {
            float bv = b3[nt * 16 + nl];
            f32x4 acc = {bv, bv, bv, bv};
            const unsigned short* wp = W3t + (nt * 16 + nl) * 256 + kb;
            for (int k0 = 0; k0 < 8; k0++) {
                short8 a = *(const short8*)(xs + arow * 512 + (((k0 * 32 + kb) * 2) ^ ((arow & 7) << 4)));
                short8 b = *(const short8*)(wp + k0 * 32);
                acc = __builtin_amdgcn_mfma_f32_16x16x32_bf16(a, b, acc, 0, 0, 0);
            }
            for (int i = 0; i < 4; i++) {
                int row = wave * 16 + (lane >> 4) * 4 + i;
                int v = v0 + row;
                if (v < N_VERT) out[(size_t)v * 64 + nt * 16 + nl] = acc[i];
            }
        }
    }
}

// ---- launch --------------------------------------------------------------

extern "C" void kernel_launch(void* const* d_in, const int* in_sizes, int n_in,
                              void* d_out, int out_size, void* d_ws, size_t ws_size,
                              hipStream_t stream) {
    const float* v_attr = (const float*)d_in[0];
    const int*   edge   = (const int*)d_in[1];      // [2, N_EDGE]; row 0 = src
    const float* e_attr = (const float*)d_in[2];
    const float* g      = (const float*)d_in[3];
    const int*   batch  = (const int*)d_in[4];
    const float* W1 = (const float*)d_in[5];
    const float* b1 = (const float*)d_in[6];
    const float* W2 = (const float*)d_in[7];
    const float* b2 = (const float*)d_in[8];
    const float* W3 = (const float*)d_in[9];
    const float* b3 = (const float*)d_in[10];
    float* out = (float*)d_out;

    unsigned char* ws = (unsigned char*)d_ws;
    unsigned int*   cnt  = (unsigned int*)(ws + 0);          // 400000 B
    unsigned int*   off  = (unsigned int*)(ws + 400384);
    unsigned int*   cur  = (unsigned int*)(ws + 800768);
    unsigned int*   part = (unsigned int*)(ws + 1201152);    // 512 B
    unsigned short* W1t  = (unsigned short*)(ws + 1201664);  // 131072 B
    unsigned short* W2t  = (unsigned short*)(ws + 1332736);  // 131072 B
    unsigned short* W3t  = (unsigned short*)(ws + 1463808);  // 32768 B
    unsigned char*  tail = ws + 1496576;                     // e_sorted OR eidx
    const size_t NEED_SORTED = 1496576ull + (size_t)N_EDGE * 64ull; // ~103.9 MB

    const int* src = edge;  // first N_EDGE ints
    const bool sorted = ws_size >= NEED_SORTED;

    k_init   <<<391,  256,  0, stream>>>(cnt);
    k_count  <<<6250, 256,  0, stream>>>(src, cnt);
    k_scan1  <<<98,   1024, 0, stream>>>(cnt, off, part);
    k_scan2  <<<1,    128,  0, stream>>>(part);
    k_addback<<<391,  256,  0, stream>>>(off, cur, part);
    k_wt     <<<576,  256,  0, stream>>>(W1, W2, W3, W1t, W2t, W3t);

    if (sorted) {
        unsigned short* es = (unsigned short*)tail;
        k_reorder<<<6250, 256, 0, stream>>>(src, e_attr, cur, es);
        k_mlp<true><<<1563, 256, 0, stream>>>(v_attr, e_attr, es, g, batch, cnt, off,
                                              (const unsigned int*)nullptr,
                                              W1t, W2t, W3t, b1, b2, b3, out);
    } else {
        unsigned int* eidx = (unsigned int*)tail;
        k_place<<<6250, 256, 0, stream>>>(src, cur, eidx);
        k_mlp<false><<<1563, 256, 0, stream>>>(v_attr, e_attr, (const unsigned short*)nullptr,
                                               g, batch, cnt, off, eidx,
                                               W1t, W2t, W3t, b1, b2, b3, out);
    }
}